// Round 15
// baseline (131.027 us; speedup 1.0000x reference)
//
#include <hip/hip_runtime.h>
#include <hip/hip_bf16.h>

typedef __bf16 bf16;
typedef __bf16 bf16x8 __attribute__((ext_vector_type(8)));
typedef __bf16 bf16x4 __attribute__((ext_vector_type(4)));
typedef __bf16 bf16x2 __attribute__((ext_vector_type(2)));
typedef float f32x4 __attribute__((ext_vector_type(4)));
typedef unsigned short u16;
typedef unsigned short u16x8 __attribute__((ext_vector_type(8)));

constexpr int kHW = 1024;
constexpr int kC  = 512;

__device__ inline float wave_sum(float v) {
#pragma unroll
    for (int o = 32; o; o >>= 1) v += __shfl_xor(v, o, 64);
    return v;
}

__device__ inline float b2f(u16 u) {
    union { float f; unsigned i; } z; z.i = ((unsigned)u) << 16; return z.f;
}

__device__ inline void gload_lds16(const void* g, void* l) {
    __builtin_amdgcn_global_load_lds(
        (const __attribute__((address_space(1))) void*)g,
        (__attribute__((address_space(3))) void*)l, 16, 0, 0);
}

#define VMCNT(n) asm volatile("s_waitcnt vmcnt(" #n ")" ::: "memory")
#define SBAR __builtin_amdgcn_s_barrier()
#define NOP do {} while (0)

// ===== GN v5: 64-ch slices, half-spatial LDS staging =======================
// 256 blocks x 512 thr; block = (sel, b, 64-ch slice). LDS stages only
// sp[0:512) (64x520 u16 = 67KB -> 2 blocks/CU). Phase 1: halfA read+stage+
// stats, halfB read+stats (discard). Phase 2a: full-line stores of halfA
// from LDS (pg = g ^ c swizzle, 8-access/bank b128 minimum). Phase 2b:
// re-read halfB (L2-hot), stage, store. Tail: weight+bias pack.
__global__ __launch_bounds__(512) void gn4_kernel(
    const float* __restrict__ x0, const float* __restrict__ s0,
    const float* __restrict__ b0, bf16* __restrict__ o0,
    const float* __restrict__ x1, const float* __restrict__ s1,
    const float* __restrict__ b1, bf16* __restrict__ o1,
    const float* __restrict__ wq, const float* __restrict__ wk,
    const float* __restrict__ wv, const float* __restrict__ wp,
    const float* __restrict__ bq, const float* __restrict__ bk,
    const float* __restrict__ bv, const float* __restrict__ bp,
    bf16* __restrict__ wdst, float* __restrict__ bpk)
{
    __shared__ u16 xs[64 * 520];           // 66.6KB, row stride 520 u16
    __shared__ float red[16];              // [wave][s,s2]
    __shared__ float ab[2][64];

    int bid = blockIdx.x;                  // 256 blocks
    int t = threadIdx.x;
    int sel = bid >> 7, b = (bid >> 3) & 15, slice = bid & 7;
    int c0 = slice * 64;

    const float* x = sel ? x1 : x0;
    const float* scale = sel ? s1 : s0;
    const float* bias  = sel ? b1 : b0;
    bf16* outT = sel ? o1 : o0;

    int row = t >> 3;                      // local channel 0..63
    int cg8 = t & 7;
    int wkey = (row >> 3) & 7;             // = channel-octet of this row
    const float* xr = x + ((size_t)b * kC + c0 + row) * kHW;

    // ---- phase 1: halfA (stage + stats) ----
    float s = 0.f, s2 = 0.f;
#pragma unroll
    for (int k = 0; k < 16; ++k) {
        int colf4 = cg8 + 8 * k;           // 0..127 -> sp 0..511
        float4 v = reinterpret_cast<const float4*>(xr)[colf4];
        int g = (colf4 * 4) >> 3;          // granule 0..63
        int h = cg8 & 1;
        int pg = g ^ wkey;
        bf16x4 r;
        r[0] = (bf16)v.x; r[1] = (bf16)v.y; r[2] = (bf16)v.z; r[3] = (bf16)v.w;
        *reinterpret_cast<bf16x4*>(&xs[row * 520 + pg * 8 + h * 4]) = r;
        s  += v.x + v.y + v.z + v.w;
        s2 += v.x*v.x + v.y*v.y + v.z*v.z + v.w*v.w;
    }
    // ---- phase 1b: halfB stats only ----
#pragma unroll
    for (int k = 0; k < 16; ++k) {
        int colf4 = 128 + cg8 + 8 * k;     // sp 512..1023
        float4 v = reinterpret_cast<const float4*>(xr)[colf4];
        s  += v.x + v.y + v.z + v.w;
        s2 += v.x*v.x + v.y*v.y + v.z*v.z + v.w*v.w;
    }
    s = wave_sum(s); s2 = wave_sum(s2);
    int lane = t & 63, wvid = t >> 6;
    if (!lane) { red[wvid * 2] = s; red[wvid * 2 + 1] = s2; }
    __syncthreads();
    if (t < 64) {
        int gi = t >> 4;                   // group of local channel t
        float ts = red[gi * 4]     + red[gi * 4 + 2];
        float t2 = red[gi * 4 + 1] + red[gi * 4 + 3];
        float mean = ts * (1.f / 16384.f);
        float var  = t2 * (1.f / 16384.f) - mean * mean;
        float inv  = rsqrtf(var + 1e-6f);
        float a = inv * scale[c0 + t];
        ab[0][t] = a;
        ab[1][t] = bias[c0 + t] - mean * a;
    }
    __syncthreads();

    // ---- phase 2a: halfA full-line stores ----
    int c = t & 7;                         // channel-octet
    int g = t >> 3;                        // granule / sp-octet, 0..63
    float av[8], dv[8];
#pragma unroll
    for (int j = 0; j < 8; ++j) { av[j] = ab[0][c * 8 + j]; dv[j] = ab[1][c * 8 + j]; }
    bf16* ob = outT + ((size_t)b * kHW) * kC + c0 + c * 8;
    {
        bf16x8 wsr[8];
#pragma unroll
        for (int j = 0; j < 8; ++j) {
            int rrow = c * 8 + j;
            int pg = g ^ c;                // wkey(rrow) = c
            u16x8 vj = *reinterpret_cast<const u16x8*>(&xs[rrow * 520 + pg * 8]);
#pragma unroll
            for (int e = 0; e < 8; ++e)
                wsr[j][e] = (bf16)(b2f(vj[e]) * av[j] + dv[j]);
        }
        int sp0 = g * 8;
#pragma unroll
        for (int e = 0; e < 8; ++e) {
            bf16x8 st;
#pragma unroll
            for (int j = 0; j < 8; ++j) st[j] = wsr[j][e];
            *reinterpret_cast<bf16x8*>(ob + (size_t)(sp0 + e) * kC) = st;
        }
    }
    __syncthreads();

    // ---- phase 2b: halfB re-read (L2-hot), stage, store ----
#pragma unroll
    for (int k = 0; k < 16; ++k) {
        int colf4 = 128 + cg8 + 8 * k;
        float4 v = reinterpret_cast<const float4*>(xr)[colf4];
        int gl = ((colf4 - 128) * 4) >> 3; // local granule 0..63
        int h = cg8 & 1;
        int pg = gl ^ wkey;
        bf16x4 r;
        r[0] = (bf16)v.x; r[1] = (bf16)v.y; r[2] = (bf16)v.z; r[3] = (bf16)v.w;
        *reinterpret_cast<bf16x4*>(&xs[row * 520 + pg * 8 + h * 4]) = r;
    }
    __syncthreads();
    {
        bf16x8 wsr[8];
#pragma unroll
        for (int j = 0; j < 8; ++j) {
            int rrow = c * 8 + j;
            int pg = g ^ c;
            u16x8 vj = *reinterpret_cast<const u16x8*>(&xs[rrow * 520 + pg * 8]);
#pragma unroll
            for (int e = 0; e < 8; ++e)
                wsr[j][e] = (bf16)(b2f(vj[e]) * av[j] + dv[j]);
        }
        int sp0 = 512 + g * 8;
#pragma unroll
        for (int e = 0; e < 8; ++e) {
            bf16x8 st;
#pragma unroll
            for (int j = 0; j < 8; ++j) st[j] = wsr[j][e];
            *reinterpret_cast<bf16x8*>(ob + (size_t)(sp0 + e) * kC) = st;
        }
    }

    // ---- tail: weight f32->bf16 pack + bias pack ----
    {
        int i = bid * 1024 + t * 2;        // 256*1024 = 262144
        float2 vq = *reinterpret_cast<const float2*>(wq + i);
        float2 vk = *reinterpret_cast<const float2*>(wk + i);
        float2 vv = *reinterpret_cast<const float2*>(wv + i);
        float2 vp = *reinterpret_cast<const float2*>(wp + i);
        bf16x2 p;
        p[0] = (bf16)vq.x; p[1] = (bf16)vq.y;
        *reinterpret_cast<bf16x2*>(wdst + i) = p;
        p[0] = (bf16)vk.x; p[1] = (bf16)vk.y;
        *reinterpret_cast<bf16x2*>(wdst + 262144 + i) = p;
        p[0] = (bf16)vv.x; p[1] = (bf16)vv.y;
        *reinterpret_cast<bf16x2*>(wdst + 2 * 262144 + i) = p;
        p[0] = (bf16)vp.x; p[1] = (bf16)vp.y;
        *reinterpret_cast<bf16x2*>(wdst + 3 * 262144 + i) = p;
        int ib = bid * 512 + t;
        if (ib < 2048) {
            int j = ib >> 9, cch = ib & 511;
            const float* sb = j == 0 ? bq : j == 1 ? bk : j == 2 ? bv : bp;
            bpk[ib] = sb[cch];
        }
    }
}

// ======== 256x256 8-phase NT GEMM, K=512. Schedule v2 =====================
// STATS (no-max softmax): writes P = exp(alpha*acc) as C, plus per-(row,bx)
// partial row-sum L into statsOut[(job*1024+row)*4 + bx].
template <int BIAS, bool RESID, typename OUT_T, bool STATS, int NBX, int NBY>
__global__ __launch_bounds__(512, 2) void gemm256(
    const bf16* __restrict__ Ab, size_t sA, int lda,
    const bf16* __restrict__ Bb, size_t sB, int ldb,
    OUT_T* __restrict__ Cb, size_t sC, int ldc,
    const float* __restrict__ biasB, int sBias,
    const float* __restrict__ residB, size_t sR,
    float alpha, float* __restrict__ statsOut)
{
    __shared__ u16 lds[65536];           // 128KB: A 8x8KB (2slot x 4q), B same
    constexpr int NT = 8;                // K = 512

    int bid = blockIdx.x, nwg = gridDim.x;
    int swz = (bid & 7) * (nwg >> 3) + (bid >> 3);
    int job = swz / (NBX * NBY), rem = swz % (NBX * NBY);
    int by = rem / NBX, bx = rem % NBX;
    int brow = by * 256, bcol = bx * 256;

    const u16* Au = reinterpret_cast<const u16*>(Ab + (size_t)job * sA);
    const u16* Bu = reinterpret_cast<const u16*>(Bb + (size_t)job * sB);

    int t = threadIdx.x;
    int lane = t & 63, w = t >> 6;
    int wm = w >> 2, wn = w & 3;
    int cc = lane & 15, nib = lane >> 4;

    int trow = t >> 3;                               // 0..63
    int gsrc = ((t & 7) ^ (trow & 7)) * 8;           // pre-swizzled src granule
    const u16* Asrc = Au + (size_t)(brow + trow) * lda + gsrc;
    const u16* Bsrc = Bu + (size_t)(bcol + trow) * ldb + gsrc;
    u16* LDSA = lds;
    u16* LDSB = lds + 32768;

#define STAGE_A(TL, Q) gload_lds16(Asrc + (size_t)(Q) * 64 * lda + (TL) * 64, \
                                   LDSA + (((TL)&1)*4 + (Q)) * 4096 + t * 8)
#define STAGE_B(TL, Q) gload_lds16(Bsrc + (size_t)(Q) * 64 * ldb + (TL) * 64, \
                                   LDSB + (((TL)&1)*4 + (Q)) * 4096 + t * 8)

    f32x4 acc[8][4] = {};
    bf16x8 afr[4][2], bfr[4][2];

#define PHASE(MH, NH, TL, STG, WTC)                                           \
  {                                                                           \
    if ((NH) == 0) {                                                          \
      _Pragma("unroll") for (int mi = 0; mi < 4; ++mi)                        \
      _Pragma("unroll") for (int kx = 0; kx < 2; ++kx)                        \
        afr[mi][kx] = *reinterpret_cast<const bf16x8*>(LDSA +                 \
            (((TL)&1)*4 + wm*2 + (MH)) * 4096 + (mi*16 + cc) * 64 +           \
            (((nib + kx*4) ^ (cc & 7)) * 8));                                 \
    }                                                                         \
    if ((MH) == 0) {                                                          \
      _Pragma("unroll") for (int ni = 0; ni < 2; ++ni)                        \
      _Pragma("unroll") for (int kx = 0; kx < 2; ++kx)                        \
        bfr[(NH)*2 + ni][kx] = *reinterpret_cast<const bf16x8*>(LDSB +        \
            (((TL)&1)*4 + wn) * 4096 + (((NH)*2 + ni)*16 + cc) * 64 +         \
            (((nib + kx*4) ^ (cc & 7)) * 8));                                 \
    }                                                                         \
    STG;                                                                      \
    SBAR;                                                                     \
    __builtin_amdgcn_s_setprio(1);                                            \
    _Pragma("unroll") for (int mi = 0; mi < 4; ++mi)                          \
    _Pragma("unroll") for (int ni = 0; ni < 2; ++ni)                          \
    _Pragma("unroll") for (int kx = 0; kx < 2; ++kx)                          \
      acc[(MH)*4 + mi][(NH)*2 + ni] = __builtin_amdgcn_mfma_f32_16x16x32_bf16(\
          afr[mi][kx], bfr[(NH)*2 + ni][kx], acc[(MH)*4 + mi][(NH)*2 + ni],   \
          0, 0, 0);                                                           \
    __builtin_amdgcn_s_setprio(0);                                            \
    WTC;                                                                      \
    SBAR;                                                                     \
  }

    // prologue: tiles 0 and 1 fully staged; wait for tile 0
    STAGE_A(0, 0); STAGE_A(0, 2); STAGE_B(0, 0); STAGE_B(0, 1);
    STAGE_B(0, 2); STAGE_B(0, 3); STAGE_A(0, 1); STAGE_A(0, 3);
    STAGE_A(1, 0); STAGE_A(1, 2); STAGE_B(1, 0); STAGE_B(1, 1);
    STAGE_B(1, 2); STAGE_B(1, 3); STAGE_A(1, 1); STAGE_A(1, 3);
    VMCNT(8);
    SBAR;

#pragma unroll
    for (int kt = 0; kt < NT; ++kt) {
        PHASE(0, 0, kt, NOP, NOP);
        PHASE(0, 1, kt,
              if (kt + 2 < NT) { STAGE_A(kt + 2, 0); STAGE_A(kt + 2, 2); },
              NOP);
        PHASE(1, 0, kt,
              if (kt + 2 < NT) { STAGE_B(kt + 2, 0); STAGE_B(kt + 2, 1); },
              NOP);
        PHASE(1, 1, kt,
              if (kt + 2 < NT) { STAGE_B(kt + 2, 2); STAGE_B(kt + 2, 3);
                                 STAGE_A(kt + 2, 1); STAGE_A(kt + 2, 3); },
              if (kt < NT - 2) { VMCNT(8); } else if (kt == NT - 2) { VMCNT(0); });
    }
#undef PHASE
#undef STAGE_A
#undef STAGE_B

#pragma unroll
    for (int m = 0; m < 8; ++m)
#pragma unroll
        for (int n = 0; n < 4; ++n)
#pragma unroll
            for (int r = 0; r < 4; ++r)
                acc[m][n][r] *= alpha;

    if constexpr (STATS) {
        // no-max softmax: acc -> exp(acc); partial row-sum over this block's
        // 256 cols; one float per (row, bx).
        float* sredS = reinterpret_cast<float*>(lds);          // [4][256]
#pragma unroll
        for (int m = 0; m < 8; ++m)
#pragma unroll
            for (int r = 0; r < 4; ++r) {
                float s_ = 0.f;
#pragma unroll
                for (int n = 0; n < 4; ++n) {
                    float e = __expf(acc[m][n][r]);
                    acc[m][n][r] = e;
                    s_ += e;
                }
                s_ += __shfl_xor(s_, 1, 64);
                s_ += __shfl_xor(s_, 2, 64);
                s_ += __shfl_xor(s_, 4, 64);
                s_ += __shfl_xor(s_, 8, 64);
                if (cc == 0)
                    sredS[wn * 256 + wm * 128 + m * 16 + nib * 4 + r] = s_;
            }
        __syncthreads();
        if (t < 256) {
            float L = sredS[t] + sredS[256 + t] + sredS[512 + t] + sredS[768 + t];
            statsOut[((size_t)(job * 1024 + brow + t)) * 4 + bx] = L;
        }
    }

    OUT_T* Cj = Cb + (size_t)job * sC;
    const float* bias = biasB + (size_t)job * sBias;
#pragma unroll
    for (int m = 0; m < 8; ++m) {
#pragma unroll
        for (int n = 0; n < 4; ++n) {
#pragma unroll
            for (int r = 0; r < 4; ++r) {
                int grow = brow + wm * 128 + m * 16 + nib * 4 + r;
                int gcol = bcol + wn * 64 + n * 16 + cc;
                float vv = acc[m][n][r];
                if (BIAS == 1) vv += bias[grow];
                if (BIAS == 2) vv += bias[gcol];
                if (RESID)     vv += residB[(size_t)job * sR + (size_t)grow * ldc + gcol];
                Cj[(size_t)grow * ldc + gcol] = (OUT_T)vv;
            }
        }
    }
}

// ======== 128x256 NT GEMM, BK=32, ring-3 slots (72KB) =====================
// NT = K/32. Per tile: 3 gload_lds (A 8KB, B 2x8KB); vmcnt(3) ledger.
// RSCALE: multiply each output row by 1/sum(statsIn[row*4+0..3]).
template <int BIAS, bool RESID, typename OUT_T, int NBX, int NBY, int NT, bool RSCALE>
__global__ __launch_bounds__(512, 4) void gemm128(
    const bf16* __restrict__ Ab, size_t sA, int lda,
    const bf16* __restrict__ Bb, size_t sB, int ldb,
    OUT_T* __restrict__ Cb, size_t sC, int ldc,
    const float* __restrict__ biasB, int sBias,
    const float* __restrict__ residB, size_t sR,
    const float* __restrict__ statsIn)
{
    __shared__ u16 lds[3 * 12288];       // 72KB: 3 slots x (A 8KB + B 16KB)

    int bid = blockIdx.x, nwg = gridDim.x;
    int swz = (bid & 7) * (nwg >> 3) + (bid >> 3);
    int job = swz / (NBX * NBY), rem = swz % (NBX * NBY);
    int by = rem / NBX, bx = rem % NBX;
    int brow = by * 128, bcol = bx * 256;

    const u16* Au = reinterpret_cast<const u16*>(Ab + (size_t)job * sA);
    const u16* Bu = reinterpret_cast<const u16*>(Bb + (size_t)job * sB);

    int t = threadIdx.x;
    int lane = t & 63, w = t >> 6;
    int wm = w >> 2, wn = w & 3;         // wm 0..1 (M), wn 0..3 (N)
    int cc = lane & 15, nib = lane >> 4;

    int trow = t >> 2;
    int gsrc = ((t & 3) ^ (trow & 3)) * 8;
    const u16* Asrc = Au + (size_t)(brow + trow) * lda + gsrc;
    const u16* Bsrc = Bu + (size_t)(bcol + trow) * ldb + gsrc;

#define STG_T(TL) {                                                           \
    u16* sl_ = lds + ((TL) % 3) * 12288;                                      \
    gload_lds16(Asrc + (TL) * 32,                       sl_ + t * 8);         \
    gload_lds16(Bsrc + (TL) * 32,                       sl_ + 4096 + t * 8);  \
    gload_lds16(Bsrc + (size_t)128 * ldb + (TL) * 32,   sl_ + 8192 + t * 8);  \
  }

    f32x4 acc[4][4] = {};

    STG_T(0); STG_T(1);
    VMCNT(3);
    SBAR;

#pragma unroll
    for (int kt = 0; kt < NT; ++kt) {
        if (kt + 2 < NT) STG_T(kt + 2);
        const u16* sb = lds + (kt % 3) * 12288;
        bf16x8 a[4], b[4];
#pragma unroll
        for (int mi = 0; mi < 4; ++mi)
            a[mi] = *reinterpret_cast<const bf16x8*>(sb +
                (wm * 64 + mi * 16 + cc) * 32 + ((nib ^ (cc & 3)) * 8));
#pragma unroll
        for (int ni = 0; ni < 4; ++ni)
            b[ni] = *reinterpret_cast<const bf16x8*>(sb + 4096 +
                (wn * 64 + ni * 16 + cc) * 32 + ((nib ^ (cc & 3)) * 8));
        __builtin_amdgcn_s_setprio(1);
#pragma unroll
        for (int mi = 0; mi < 4; ++mi)
#pragma unroll
            for (int ni = 0; ni < 4; ++ni)
                acc[mi][ni] = __builtin_amdgcn_mfma_f32_16x16x32_bf16(
                    a[mi], b[ni], acc[mi][ni], 0, 0, 0);
        __builtin_amdgcn_s_setprio(0);
        if (kt < NT - 2) { VMCNT(3); } else if (kt == NT - 2) { VMCNT(0); }
        SBAR;
    }
#undef STG_T

    float* Ls = reinterpret_cast<float*>(lds);   // tiles dead after loop
    if constexpr (RSCALE) {
        __syncthreads();
        if (t < 128) {
            float4 sv = *reinterpret_cast<const float4*>(
                statsIn + ((size_t)(job * 1024 + brow + t)) * 4);
            Ls[t] = 1.0f / (sv.x + sv.y + sv.z + sv.w);
        }
        __syncthreads();
    }

    OUT_T* Cj = Cb + (size_t)job * sC;
    const float* bias = biasB + (size_t)job * sBias;
#pragma unroll
    for (int mi = 0; mi < 4; ++mi) {
#pragma unroll
        for (int ni = 0; ni < 4; ++ni) {
#pragma unroll
            for (int r = 0; r < 4; ++r) {
                int grow = brow + wm * 64 + mi * 16 + nib * 4 + r;
                int gcol = bcol + wn * 64 + ni * 16 + cc;
                float vv = acc[mi][ni][r];
                if constexpr (RSCALE) vv *= Ls[wm * 64 + mi * 16 + nib * 4 + r];
                if (BIAS == 1) vv += bias[grow];
                if (BIAS == 2) vv += bias[gcol];
                if (RESID)     vv += residB[(size_t)job * sR + (size_t)grow * ldc + gcol];
                Cj[(size_t)grow * ldc + gcol] = (OUT_T)vv;
            }
        }
    }
}

extern "C" void kernel_launch(void* const* d_in, const int* in_sizes, int n_in,
                              void* d_out, int out_size, void* d_ws, size_t ws_size,
                              hipStream_t stream)
{
    const float* x   = (const float*)d_in[0];
    const float* y   = (const float*)d_in[1];
    const float* ns  = (const float*)d_in[2];
    const float* nb  = (const float*)d_in[3];
    const float* n1s = (const float*)d_in[4];
    const float* n1b = (const float*)d_in[5];
    const float* wq  = (const float*)d_in[6];
    const float* bq  = (const float*)d_in[7];
    const float* wk  = (const float*)d_in[8];
    const float* bk  = (const float*)d_in[9];
    const float* wv  = (const float*)d_in[10];
    const float* bv  = (const float*)d_in[11];
    const float* wp  = (const float*)d_in[12];
    const float* bp  = (const float*)d_in[13];
    float* out = (float*)d_out;

    char* ws = (char*)d_ws;
    bf16* wbf  = (bf16*)ws;                          // 2 MB weights bf16
    float* bpk = (float*)(ws + 2097152);             // 8 KB biases
    bf16* ynT = (bf16*)(ws + 2105344);               // [b][hw][c]
    bf16* hnT = ynT + 8388608;
    bf16* qT  = hnT + 8388608;
    bf16* kT  = qT  + 8388608;
    bf16* v   = kT  + 8388608;                       // [b][c][hw]
    float* stats = (float*)ynT;                      // ynT dead after q/k conv
    bf16* aoT = qT;                                  // qT dead after QK^T
    bf16* P   = (bf16*)(ws + 2105344 + 5ull * 16777216);   // 32 MB bf16

    const size_t sBC = (size_t)kHW * kC;
    const float scl = 0.044194173824159216f;         // 512^-0.5

    // GN(x)->hnT, GN(y)->ynT, weight+bias pack — one launch, 256 blocks
    gn4_kernel<<<256, 512, 0, stream>>>(
        x, ns, nb, hnT, y, n1s, n1b, ynT,
        wq, wk, wv, wp, bq, bk, bv, bp, wbf, bpk);

    // q & k convs fused (jobs 0/1): out_T[i][o] = in_T[i][c]·W[o][c] + b[o]
    gemm256<2, false, bf16, false, 2, 64><<<256, 512, 0, stream>>>(
        ynT, 8388608, 512, wbf, 262144, 512, qT, 8388608, 512,
        bpk, 512, nullptr, 0, 1.f, nullptr);
    // v conv per batch: v[o][n] = wv[o][c]·hnT[n][c] + bv[o]   (K=512, NT=16)
    gemm128<1, false, bf16, 4, 4, 16, false><<<256, 512, 0, stream>>>(
        wbf + 2 * 262144, 0, 512, hnT, sBC, 512, v, sBC, 1024,
        bpk + 1024, 0, nullptr, 0, nullptr);
    // QK^T -> P = exp(scl*S) bf16 + partial row-sums L per (row, bx)
    gemm256<0, false, bf16, true, 4, 4><<<256, 512, 0, stream>>>(
        qT, sBC, 512, kT, sBC, 512, P, 1048576, 1024,
        bpk, 0, nullptr, 0, scl, stats);
    // PV as pure GEMM (K=1024, NT=32) + 1/L: aoT[i][c] = P[i][:]·v[c][:] / L_i
    gemm128<0, false, bf16, 2, 8, 32, true><<<256, 512, 0, stream>>>(
        P, (size_t)1048576, 1024, v, sBC, 1024, aoT, sBC, 512,
        bpk, 0, nullptr, 0, stats);
    // proj + bias + residual   (K=512, NT=16)
    gemm128<1, true, float, 4, 4, 16, false><<<256, 512, 0, stream>>>(
        wbf + 3 * 262144, 0, 512, aoT, sBC, 512, out, sBC, 1024,
        bpk + 1536, 0, x, sBC, nullptr);
}

// Round 16
// 124.399 us; speedup vs baseline: 1.0533x; 1.0533x over previous
//
#include <hip/hip_runtime.h>
#include <hip/hip_bf16.h>

typedef __bf16 bf16;
typedef __bf16 bf16x8 __attribute__((ext_vector_type(8)));
typedef __bf16 bf16x4 __attribute__((ext_vector_type(4)));
typedef float f32x4 __attribute__((ext_vector_type(4)));
typedef unsigned short u16;
typedef unsigned short u16x8 __attribute__((ext_vector_type(8)));

constexpr int kHW = 1024;
constexpr int kC  = 512;

__device__ inline float wave_sum(float v) {
#pragma unroll
    for (int o = 32; o; o >>= 1) v += __shfl_xor(v, o, 64);
    return v;
}

__device__ inline float b2f(u16 u) {
    union { float f; unsigned i; } z; z.i = ((unsigned)u) << 16; return z.f;
}

__device__ inline void gload_lds16(const void* g, void* l) {
    __builtin_amdgcn_global_load_lds(
        (const __attribute__((address_space(1))) void*)g,
        (__attribute__((address_space(3))) void*)l, 16, 0, 0);
}

#define VMCNT(n) asm volatile("s_waitcnt vmcnt(" #n ")" ::: "memory")
#define SBAR __builtin_amdgcn_s_barrier()
#define NOP do {} while (0)

// ===== fused: GroupNorm(x)->hnT, GroupNorm(y)->ynT, weights f32->bf16 =====
__global__ __launch_bounds__(256) void gn2w_kernel(
    const float* __restrict__ x0, const float* __restrict__ s0,
    const float* __restrict__ b0, bf16* __restrict__ o0,
    const float* __restrict__ x1, const float* __restrict__ s1,
    const float* __restrict__ b1, bf16* __restrict__ o1,
    const float* __restrict__ wq, const float* __restrict__ wk,
    const float* __restrict__ wv, const float* __restrict__ wp,
    const float* __restrict__ bq, const float* __restrict__ bk,
    const float* __restrict__ bv, const float* __restrict__ bp,
    bf16* __restrict__ wdst, float* __restrict__ bpk)
{
    int bid = blockIdx.x;
    int t = threadIdx.x;
    if (bid >= 1024) {                    // weight-pack blocks
        int i = (bid - 1024) * 256 + t;
        wdst[i]            = (bf16)wq[i];
        wdst[262144 + i]   = (bf16)wk[i];
        wdst[2*262144 + i] = (bf16)wv[i];
        wdst[3*262144 + i] = (bf16)wp[i];
        if (i < 2048) {
            int j = i >> 9, c = i & 511;
            const float* s = j == 0 ? bq : j == 1 ? bk : j == 2 ? bv : bp;
            bpk[i] = s[c];
        }
        return;
    }

    __shared__ u16 xs[16][1032];          // raw bf16 tile, 33KB
    __shared__ float red[8];
    __shared__ float ab[2][16];

    // XCD-locality decode: xcd = bid&7 owns 4 (sel,b) pairs, each with all 32 g
    int xcd = bid & 7, idx = bid >> 3;    // idx 0..127
    int pair = xcd * 4 + (idx >> 5);      // 0..31
    int g = idx & 31;
    int sel = pair >> 4;
    int b = pair & 15;

    const float* x = sel ? x1 : x0;
    const float* scale = sel ? s1 : s0;
    const float* bias  = sel ? b1 : b0;
    bf16* outT = sel ? o1 : o0;

    int c0 = g * 16;
    const float* xg = x + ((size_t)b * kC + c0) * kHW;

    float s = 0.f, s2 = 0.f;
    const float4* xg4 = reinterpret_cast<const float4*>(xg);
#pragma unroll
    for (int i = 0; i < 16; ++i) {
        float4 v = xg4[t + i * 256];      // channel i, col 4t
        bf16x4 r;
        r[0] = (bf16)v.x; r[1] = (bf16)v.y; r[2] = (bf16)v.z; r[3] = (bf16)v.w;
        *reinterpret_cast<bf16x4*>(&xs[i][t * 4]) = r;
        s  += v.x + v.y + v.z + v.w;
        s2 += v.x*v.x + v.y*v.y + v.z*v.z + v.w*v.w;
    }
    s = wave_sum(s); s2 = wave_sum(s2);
    int lane = t & 63, wid = t >> 6;
    if (!lane) { red[wid] = s; red[4 + wid] = s2; }
    __syncthreads();
    float ts = red[0] + red[1] + red[2] + red[3];
    float t2 = red[4] + red[5] + red[6] + red[7];
    float mean = ts * (1.f / 16384.f);
    float var  = t2 * (1.f / 16384.f) - mean * mean;
    float inv  = rsqrtf(var + 1e-6f);

    if (t < 16) {
        float a = inv * scale[c0 + t];
        ab[0][t] = a;
        ab[1][t] = bias[c0 + t] - mean * a;
    }
    __syncthreads();

    int cg = t & 3, spw = t >> 2;         // 4 channel-groups x 64 rows
    float a0 = ab[0][cg*4],   a1 = ab[0][cg*4+1],
          a2 = ab[0][cg*4+2], a3 = ab[0][cg*4+3];
    float d0 = ab[1][cg*4],   d1 = ab[1][cg*4+1],
          d2 = ab[1][cg*4+2], d3 = ab[1][cg*4+3];
    bf16* ob = outT + (size_t)b * kHW * kC + c0 + cg * 4;
#pragma unroll
    for (int i = 0; i < 16; ++i) {
        int sp = spw + i * 64;
        bf16x4 w;
        w[0] = (bf16)(b2f(xs[cg*4 + 0][sp]) * a0 + d0);
        w[1] = (bf16)(b2f(xs[cg*4 + 1][sp]) * a1 + d1);
        w[2] = (bf16)(b2f(xs[cg*4 + 2][sp]) * a2 + d2);
        w[3] = (bf16)(b2f(xs[cg*4 + 3][sp]) * a3 + d3);
        *reinterpret_cast<bf16x4*>(ob + (size_t)sp * kC) = w;
    }
}

// ======== 256x256 8-phase NT GEMM, K=512. Schedule v2 =====================
// STATS (no-max softmax): writes P = exp(alpha*acc) as C, plus per-(row,bx)
// partial row-sum L into statsOut[(job*1024+row)*4 + bx].
template <int BIAS, bool RESID, typename OUT_T, bool STATS, int NBX, int NBY>
__global__ __launch_bounds__(512, 2) void gemm256(
    const bf16* __restrict__ Ab, size_t sA, int lda,
    const bf16* __restrict__ Bb, size_t sB, int ldb,
    OUT_T* __restrict__ Cb, size_t sC, int ldc,
    const float* __restrict__ biasB, int sBias,
    const float* __restrict__ residB, size_t sR,
    float alpha, float* __restrict__ statsOut)
{
    __shared__ u16 lds[65536];           // 128KB: A 8x8KB (2slot x 4q), B same
    constexpr int NT = 8;                // K = 512

    int bid = blockIdx.x, nwg = gridDim.x;
    int swz = (bid & 7) * (nwg >> 3) + (bid >> 3);
    int job = swz / (NBX * NBY), rem = swz % (NBX * NBY);
    int by = rem / NBX, bx = rem % NBX;
    int brow = by * 256, bcol = bx * 256;

    const u16* Au = reinterpret_cast<const u16*>(Ab + (size_t)job * sA);
    const u16* Bu = reinterpret_cast<const u16*>(Bb + (size_t)job * sB);

    int t = threadIdx.x;
    int lane = t & 63, w = t >> 6;
    int wm = w >> 2, wn = w & 3;
    int cc = lane & 15, nib = lane >> 4;

    int trow = t >> 3;                               // 0..63
    int gsrc = ((t & 7) ^ (trow & 7)) * 8;           // pre-swizzled src granule
    const u16* Asrc = Au + (size_t)(brow + trow) * lda + gsrc;
    const u16* Bsrc = Bu + (size_t)(bcol + trow) * ldb + gsrc;
    u16* LDSA = lds;
    u16* LDSB = lds + 32768;

#define STAGE_A(TL, Q) gload_lds16(Asrc + (size_t)(Q) * 64 * lda + (TL) * 64, \
                                   LDSA + (((TL)&1)*4 + (Q)) * 4096 + t * 8)
#define STAGE_B(TL, Q) gload_lds16(Bsrc + (size_t)(Q) * 64 * ldb + (TL) * 64, \
                                   LDSB + (((TL)&1)*4 + (Q)) * 4096 + t * 8)

    f32x4 acc[8][4] = {};
    bf16x8 afr[4][2], bfr[4][2];

#define PHASE(MH, NH, TL, STG, WTC)                                           \
  {                                                                           \
    if ((NH) == 0) {                                                          \
      _Pragma("unroll") for (int mi = 0; mi < 4; ++mi)                        \
      _Pragma("unroll") for (int kx = 0; kx < 2; ++kx)                        \
        afr[mi][kx] = *reinterpret_cast<const bf16x8*>(LDSA +                 \
            (((TL)&1)*4 + wm*2 + (MH)) * 4096 + (mi*16 + cc) * 64 +           \
            (((nib + kx*4) ^ (cc & 7)) * 8));                                 \
    }                                                                         \
    if ((MH) == 0) {                                                          \
      _Pragma("unroll") for (int ni = 0; ni < 2; ++ni)                        \
      _Pragma("unroll") for (int kx = 0; kx < 2; ++kx)                        \
        bfr[(NH)*2 + ni][kx] = *reinterpret_cast<const bf16x8*>(LDSB +        \
            (((TL)&1)*4 + wn) * 4096 + (((NH)*2 + ni)*16 + cc) * 64 +         \
            (((nib + kx*4) ^ (cc & 7)) * 8));                                 \
    }                                                                         \
    STG;                                                                      \
    SBAR;                                                                     \
    __builtin_amdgcn_s_setprio(1);                                            \
    _Pragma("unroll") for (int mi = 0; mi < 4; ++mi)                          \
    _Pragma("unroll") for (int ni = 0; ni < 2; ++ni)                          \
    _Pragma("unroll") for (int kx = 0; kx < 2; ++kx)                          \
      acc[(MH)*4 + mi][(NH)*2 + ni] = __builtin_amdgcn_mfma_f32_16x16x32_bf16(\
          afr[mi][kx], bfr[(NH)*2 + ni][kx], acc[(MH)*4 + mi][(NH)*2 + ni],   \
          0, 0, 0);                                                           \
    __builtin_amdgcn_s_setprio(0);                                            \
    WTC;                                                                      \
    SBAR;                                                                     \
  }

    // prologue: tiles 0 and 1 fully staged; wait for tile 0
    STAGE_A(0, 0); STAGE_A(0, 2); STAGE_B(0, 0); STAGE_B(0, 1);
    STAGE_B(0, 2); STAGE_B(0, 3); STAGE_A(0, 1); STAGE_A(0, 3);
    STAGE_A(1, 0); STAGE_A(1, 2); STAGE_B(1, 0); STAGE_B(1, 1);
    STAGE_B(1, 2); STAGE_B(1, 3); STAGE_A(1, 1); STAGE_A(1, 3);
    VMCNT(8);
    SBAR;

#pragma unroll
    for (int kt = 0; kt < NT; ++kt) {
        PHASE(0, 0, kt, NOP, NOP);
        PHASE(0, 1, kt,
              if (kt + 2 < NT) { STAGE_A(kt + 2, 0); STAGE_A(kt + 2, 2); },
              NOP);
        PHASE(1, 0, kt,
              if (kt + 2 < NT) { STAGE_B(kt + 2, 0); STAGE_B(kt + 2, 1); },
              NOP);
        PHASE(1, 1, kt,
              if (kt + 2 < NT) { STAGE_B(kt + 2, 2); STAGE_B(kt + 2, 3);
                                 STAGE_A(kt + 2, 1); STAGE_A(kt + 2, 3); },
              if (kt < NT - 2) { VMCNT(8); } else if (kt == NT - 2) { VMCNT(0); });
    }
#undef PHASE
#undef STAGE_A
#undef STAGE_B

#pragma unroll
    for (int m = 0; m < 8; ++m)
#pragma unroll
        for (int n = 0; n < 4; ++n)
#pragma unroll
            for (int r = 0; r < 4; ++r)
                acc[m][n][r] *= alpha;

    if constexpr (STATS) {
        // no-max softmax: acc -> exp(acc); partial row-sum over this block's
        // 256 cols; one float per (row, bx).
        float* sredS = reinterpret_cast<float*>(lds);          // [4][256]
#pragma unroll
        for (int m = 0; m < 8; ++m)
#pragma unroll
            for (int r = 0; r < 4; ++r) {
                float s_ = 0.f;
#pragma unroll
                for (int n = 0; n < 4; ++n) {
                    float e = __expf(acc[m][n][r]);
                    acc[m][n][r] = e;
                    s_ += e;
                }
                s_ += __shfl_xor(s_, 1, 64);
                s_ += __shfl_xor(s_, 2, 64);
                s_ += __shfl_xor(s_, 4, 64);
                s_ += __shfl_xor(s_, 8, 64);
                if (cc == 0)
                    sredS[wn * 256 + wm * 128 + m * 16 + nib * 4 + r] = s_;
            }
        __syncthreads();
        if (t < 256) {
            float L = sredS[t] + sredS[256 + t] + sredS[512 + t] + sredS[768 + t];
            statsOut[((size_t)(job * 1024 + brow + t)) * 4 + bx] = L;
        }
    }

    OUT_T* Cj = Cb + (size_t)job * sC;
    const float* bias = biasB + (size_t)job * sBias;
#pragma unroll
    for (int m = 0; m < 8; ++m) {
#pragma unroll
        for (int n = 0; n < 4; ++n) {
#pragma unroll
            for (int r = 0; r < 4; ++r) {
                int grow = brow + wm * 128 + m * 16 + nib * 4 + r;
                int gcol = bcol + wn * 64 + n * 16 + cc;
                float vv = acc[m][n][r];
                if (BIAS == 1) vv += bias[grow];
                if (BIAS == 2) vv += bias[gcol];
                if (RESID)     vv += residB[(size_t)job * sR + (size_t)grow * ldc + gcol];
                Cj[(size_t)grow * ldc + gcol] = (OUT_T)vv;
            }
        }
    }
}

// ======== 128x256 NT GEMM, BK=64, ring-3 slots, 1 barrier/tile ============
// NT = K/64 (template). RSCALE: multiply each output row by
// 1 / sum(statsIn[(job*1024+row)*4 + 0..3])  (softmax-finish for PV).
template <int BIAS, bool RESID, typename OUT_T, int NBX, int NBY, int NT, bool RSCALE>
__global__ __launch_bounds__(512, 2) void gemm128(
    const bf16* __restrict__ Ab, size_t sA, int lda,
    const bf16* __restrict__ Bb, size_t sB, int ldb,
    OUT_T* __restrict__ Cb, size_t sC, int ldc,
    const float* __restrict__ biasB, int sBias,
    const float* __restrict__ residB, size_t sR,
    const float* __restrict__ statsIn)
{
    __shared__ u16 lds[3 * 24576];       // 144KB: 3 slots x (A 16KB + B 32KB)

    int bid = blockIdx.x, nwg = gridDim.x;
    int swz = (bid & 7) * (nwg >> 3) + (bid >> 3);
    int job = swz / (NBX * NBY), rem = swz % (NBX * NBY);
    int by = rem / NBX, bx = rem % NBX;
    int brow = by * 128, bcol = bx * 256;

    const u16* Au = reinterpret_cast<const u16*>(Ab + (size_t)job * sA);
    const u16* Bu = reinterpret_cast<const u16*>(Bb + (size_t)job * sB);

    int t = threadIdx.x;
    int lane = t & 63, w = t >> 6;
    int wm = w >> 2, wn = w & 3;         // wm 0..1 (M), wn 0..3 (N)
    int cc = lane & 15, nib = lane >> 4;

    int trow = t >> 3;
    int gsrc = ((t & 7) ^ (trow & 7)) * 8;
    const u16* Asrc = Au + (size_t)(brow + trow) * lda + gsrc;
    const u16* Bsrc = Bu + (size_t)(bcol + trow) * ldb + gsrc;

#define STG_T(TL) {                                                           \
    u16* sl_ = lds + ((TL) % 3) * 24576;                                      \
    gload_lds16(Asrc + (TL) * 64,                          sl_ + t * 8);      \
    gload_lds16(Asrc + (size_t)64 * lda + (TL) * 64,       sl_ + 4096 + t*8); \
    gload_lds16(Bsrc + (TL) * 64,                          sl_ + 8192 + t*8); \
    gload_lds16(Bsrc + (size_t)64  * ldb + (TL) * 64,      sl_ + 12288 + t*8);\
    gload_lds16(Bsrc + (size_t)128 * ldb + (TL) * 64,      sl_ + 16384 + t*8);\
    gload_lds16(Bsrc + (size_t)192 * ldb + (TL) * 64,      sl_ + 20480 + t*8);\
  }

    f32x4 acc[4][4] = {};

    STG_T(0); STG_T(1);
    VMCNT(6);
    SBAR;

#pragma unroll
    for (int kt = 0; kt < NT; ++kt) {
        if (kt + 2 < NT) STG_T(kt + 2);
        const u16* sb = lds + (kt % 3) * 24576;
        bf16x8 a[4][2], b[4][2];
#pragma unroll
        for (int mi = 0; mi < 4; ++mi)
#pragma unroll
            for (int kx = 0; kx < 2; ++kx)
                a[mi][kx] = *reinterpret_cast<const bf16x8*>(sb +
                    wm * 4096 + (mi*16 + cc) * 64 + (((nib + kx*4) ^ (cc & 7)) * 8));
#pragma unroll
        for (int ni = 0; ni < 4; ++ni)
#pragma unroll
            for (int kx = 0; kx < 2; ++kx)
                b[ni][kx] = *reinterpret_cast<const bf16x8*>(sb + 8192 +
                    wn * 4096 + (ni*16 + cc) * 64 + (((nib + kx*4) ^ (cc & 7)) * 8));
        __builtin_amdgcn_s_setprio(1);
#pragma unroll
        for (int mi = 0; mi < 4; ++mi)
#pragma unroll
            for (int ni = 0; ni < 4; ++ni)
#pragma unroll
                for (int kx = 0; kx < 2; ++kx)
                    acc[mi][ni] = __builtin_amdgcn_mfma_f32_16x16x32_bf16(
                        a[mi][kx], b[ni][kx], acc[mi][ni], 0, 0, 0);
        __builtin_amdgcn_s_setprio(0);
        if (kt < NT - 2) { VMCNT(6); } else if (kt == NT - 2) { VMCNT(0); }
        SBAR;
    }
#undef STG_T

    float* Ls = reinterpret_cast<float*>(lds);   // tiles dead after loop
    if constexpr (RSCALE) {
        __syncthreads();
        if (t < 128) {
            float4 sv = *reinterpret_cast<const float4*>(
                statsIn + ((size_t)(job * 1024 + brow + t)) * 4);
            Ls[t] = 1.0f / (sv.x + sv.y + sv.z + sv.w);
        }
        __syncthreads();
    }

    OUT_T* Cj = Cb + (size_t)job * sC;
    const float* bias = biasB + (size_t)job * sBias;
#pragma unroll
    for (int mi = 0; mi < 4; ++mi) {
#pragma unroll
        for (int ni = 0; ni < 4; ++ni) {
#pragma unroll
            for (int r = 0; r < 4; ++r) {
                int grow = brow + wm * 64 + mi * 16 + nib * 4 + r;
                int gcol = bcol + wn * 64 + ni * 16 + cc;
                float vv = acc[mi][ni][r];
                if constexpr (RSCALE) vv *= Ls[wm * 64 + mi * 16 + nib * 4 + r];
                if (BIAS == 1) vv += bias[grow];
                if (BIAS == 2) vv += bias[gcol];
                if (RESID)     vv += residB[(size_t)job * sR + (size_t)grow * ldc + gcol];
                Cj[(size_t)grow * ldc + gcol] = (OUT_T)vv;
            }
        }
    }
}

extern "C" void kernel_launch(void* const* d_in, const int* in_sizes, int n_in,
                              void* d_out, int out_size, void* d_ws, size_t ws_size,
                              hipStream_t stream)
{
    const float* x   = (const float*)d_in[0];
    const float* y   = (const float*)d_in[1];
    const float* ns  = (const float*)d_in[2];
    const float* nb  = (const float*)d_in[3];
    const float* n1s = (const float*)d_in[4];
    const float* n1b = (const float*)d_in[5];
    const float* wq  = (const float*)d_in[6];
    const float* bq  = (const float*)d_in[7];
    const float* wk  = (const float*)d_in[8];
    const float* bk  = (const float*)d_in[9];
    const float* wv  = (const float*)d_in[10];
    const float* bv  = (const float*)d_in[11];
    const float* wp  = (const float*)d_in[12];
    const float* bp  = (const float*)d_in[13];
    float* out = (float*)d_out;

    char* ws = (char*)d_ws;
    bf16* wbf  = (bf16*)ws;                          // 2 MB weights bf16
    float* bpk = (float*)(ws + 2097152);             // 8 KB biases
    bf16* ynT = (bf16*)(ws + 2105344);               // [b][hw][c]
    bf16* hnT = ynT + 8388608;
    bf16* qT  = hnT + 8388608;
    bf16* kT  = qT  + 8388608;
    bf16* v   = kT  + 8388608;                       // [b][c][hw]
    float* stats = (float*)ynT;                      // ynT dead after q/k conv
    bf16* aoT = qT;                                  // qT dead after QK^T
    bf16* P   = (bf16*)(ws + 2105344 + 5ull * 16777216);   // 32 MB bf16

    const size_t sBC = (size_t)kHW * kC;
    const float scl = 0.044194173824159216f;         // 512^-0.5

    // GN(x)->hnT, GN(y)->ynT, weight pack — one launch
    gn2w_kernel<<<2048, 256, 0, stream>>>(
        x, ns, nb, hnT, y, n1s, n1b, ynT,
        wq, wk, wv, wp, bq, bk, bv, bp, wbf, bpk);

    // q & k convs fused (jobs 0/1): out_T[i][o] = in_T[i][c]·W[o][c] + b[o]
    gemm256<2, false, bf16, false, 2, 64><<<256, 512, 0, stream>>>(
        ynT, 8388608, 512, wbf, 262144, 512, qT, 8388608, 512,
        bpk, 512, nullptr, 0, 1.f, nullptr);
    // v conv per batch: v[o][n] = wv[o][c]·hnT[n][c] + bv[o]   (K=512, NT=8)
    gemm128<1, false, bf16, 4, 4, 8, false><<<256, 512, 0, stream>>>(
        wbf + 2 * 262144, 0, 512, hnT, sBC, 512, v, sBC, 1024,
        bpk + 1024, 0, nullptr, 0, nullptr);
    // QK^T -> P = exp(scl*S) bf16 + partial row-sums L per (row, bx)
    gemm256<0, false, bf16, true, 4, 4><<<256, 512, 0, stream>>>(
        qT, sBC, 512, kT, sBC, 512, P, 1048576, 1024,
        bpk, 0, nullptr, 0, scl, stats);
    // PV as pure GEMM (K=1024, NT=16) + 1/L: aoT[i][c] = P[i][:]·v[c][:] / L_i
    gemm128<0, false, bf16, 2, 8, 16, true><<<256, 512, 0, stream>>>(
        P, (size_t)1048576, 1024, v, sBC, 1024, aoT, sBC, 512,
        bpk, 0, nullptr, 0, stats);
    // proj + bias + residual   (K=512, NT=8)
    gemm128<1, true, float, 4, 4, 8, false><<<256, 512, 0, stream>>>(
        wbf + 3 * 262144, 0, 512, aoT, sBC, 512, out, sBC, 1024,
        bpk + 1536, 0, x, sBC, nullptr);
}